// Round 7
// baseline (582.188 us; speedup 1.0000x reference)
//
#include <hip/hip_runtime.h>
#include <stdint.h>

typedef unsigned short ushort_t;
typedef unsigned long long u64_t;
typedef __attribute__((ext_vector_type(4))) float f32x4;
typedef __attribute__((ext_vector_type(8))) short s16x8;

#define S1_ELEMS ((size_t)1568*64*512)   // 51,380,224 elements per q/k/v/ao buffer

// ---------- bf16 helpers (RNE)
__device__ __forceinline__ ushort_t f2bf(float f) {
  unsigned u = __builtin_bit_cast(unsigned, f);
  u = u + 0x7fffu + ((u >> 16) & 1u);
  return (ushort_t)(u >> 16);
}

// ---------- async global->LDS, 16B per lane (dest = uniform base + lane*16)
__device__ __forceinline__ void gl_lds16(const ushort_t* g, ushort_t* l) {
  typedef __attribute__((address_space(1))) void gvoid;
  typedef __attribute__((address_space(3))) void lvoid;
  __builtin_amdgcn_global_load_lds((gvoid*)(ushort_t*)g, (lvoid*)l, 16, 0, 0);
}

// ---------- kernel 1: f32 -> bf16 (weights only now)
__global__ void k_convert_hi(const float* __restrict__ src, ushort_t* __restrict__ hi, long n4) {
  long i = (long)blockIdx.x * blockDim.x + threadIdx.x;
  long stride = (long)gridDim.x * blockDim.x;
  for (; i < n4; i += stride) {
    float4 v = ((const float4*)src)[i];
    ushort4 h;
    h.x = f2bf(v.x); h.y = f2bf(v.y); h.z = f2bf(v.z); h.w = f2bf(v.w);
    ((ushort4*)hi)[i] = h;
  }
}

// ---------- kernel 1b: precompute bias[h][rr][cc] = table[rel_idx[rr,cc]*16+h]
__global__ void k_bias(const float* __restrict__ table, const int* __restrict__ rel_idx,
                       float* __restrict__ bias) {
  int i = blockIdx.x * 256 + threadIdx.x;   // 65536 total
  int h = i >> 12, rc = i & 4095;
  bias[i] = table[rel_idx[rc] * 16 + h];
}

// ================= shared 256x256 BK=64 loop, bf16 A+B via gl_lds16 (proj).
__device__ __forceinline__ void gemm256_loop(
    ushort_t* lds, const ushort_t* pA, const ushort_t* pB,
    int w, int lane, int wm, int wn, f32x4 (&acc)[8][4]) {
  #pragma unroll
  for (int q = 0; q < 2; q++) {
    gl_lds16(pA + q*8192 +  0, lds + ((2*w + q)*2 + 0)*512);
    gl_lds16(pA + q*8192 + 32, lds + ((2*w + q)*2 + 1)*512);
    gl_lds16(pB + q*8192 +  0, lds + 16384 + ((2*w + q)*2 + 0)*512);
    gl_lds16(pB + q*8192 + 32, lds + 16384 + ((2*w + q)*2 + 1)*512);
  }
  asm volatile("s_waitcnt vmcnt(0)" ::: "memory");
  __builtin_amdgcn_s_barrier();

  for (int tau = 0; tau < 8; ++tau) {
    ushort_t* bufR = lds + (tau & 1)*32768;
    ushort_t* bufW = lds + ((tau & 1) ^ 1)*32768;
    if (tau < 7) {
      int ko = (tau + 1)*64;
      #pragma unroll
      for (int q = 0; q < 2; q++) {
        gl_lds16(pA + q*8192 + ko,      bufW + ((2*w + q)*2 + 0)*512);
        gl_lds16(pA + q*8192 + ko + 32, bufW + ((2*w + q)*2 + 1)*512);
        gl_lds16(pB + q*8192 + ko,      bufW + 16384 + ((2*w + q)*2 + 0)*512);
        gl_lds16(pB + q*8192 + ko + 32, bufW + 16384 + ((2*w + q)*2 + 1)*512);
      }
    }
    s16x8 af[4][2], bf[4][2];
    #pragma unroll
    for (int t = 0; t < 4; t++)
      #pragma unroll
      for (int kh = 0; kh < 2; kh++) {
        af[t][kh] = *(const s16x8*)&bufR[((wm*8 + t)*2 + kh)*512 + lane*8];
        bf[t][kh] = *(const s16x8*)&bufR[16384 + ((wn*4 + t)*2 + kh)*512 + lane*8];
      }
    __builtin_amdgcn_s_barrier();
    asm volatile("s_waitcnt lgkmcnt(0)" ::: "memory");
    __builtin_amdgcn_sched_barrier(0);
    __builtin_amdgcn_s_setprio(1);
    #pragma unroll
    for (int t = 0; t < 4; t++)
      #pragma unroll
      for (int tb = 0; tb < 4; tb++) {
        acc[t][tb] = __builtin_amdgcn_mfma_f32_16x16x32_bf16(af[t][0], bf[tb][0], acc[t][tb], 0, 0, 0);
        acc[t][tb] = __builtin_amdgcn_mfma_f32_16x16x32_bf16(af[t][1], bf[tb][1], acc[t][tb], 0, 0, 0);
      }
    __builtin_amdgcn_s_setprio(0);
    s16x8 ag[4][2];
    #pragma unroll
    for (int t = 0; t < 4; t++)
      #pragma unroll
      for (int kh = 0; kh < 2; kh++)
        ag[t][kh] = *(const s16x8*)&bufR[((wm*8 + 4 + t)*2 + kh)*512 + lane*8];
    asm volatile("s_waitcnt lgkmcnt(0)" ::: "memory");
    __builtin_amdgcn_sched_barrier(0);
    __builtin_amdgcn_s_setprio(1);
    #pragma unroll
    for (int t = 0; t < 4; t++)
      #pragma unroll
      for (int tb = 0; tb < 4; tb++) {
        acc[4 + t][tb] = __builtin_amdgcn_mfma_f32_16x16x32_bf16(ag[t][0], bf[tb][0], acc[4 + t][tb], 0, 0, 0);
        acc[4 + t][tb] = __builtin_amdgcn_mfma_f32_16x16x32_bf16(ag[t][1], bf[tb][1], acc[4 + t][tb], 0, 0, 0);
      }
    __builtin_amdgcn_s_setprio(0);
    asm volatile("s_waitcnt vmcnt(0)" ::: "memory");
    __builtin_amdgcn_s_barrier();
  }
}

// ================= QKV GEMM: fused f32->bf16 convert in A-staging (reg-staged,
// issue-early / write-late), B via gl_lds16. Swizzled conflict-free epilogue.
__global__ __launch_bounds__(512, 2) void k_gemm_qkv(
    const float* __restrict__ xf, const ushort_t* __restrict__ wh,
    ushort_t* __restrict__ qh, ushort_t* __restrict__ kh, ushort_t* __restrict__ vt) {
  extern __shared__ __align__(16) ushort_t lds[];
  const int tid = threadIdx.x, w = tid >> 6, lane = tid & 63;
  const int g = lane >> 4, l15 = lane & 15;
  const int wm = w >> 2, wn = w & 3;
  int flat = blockIdx.x;                 // 2352 = 8*294, bijective XCD swizzle
  int swz = (flat & 7) * 294 + (flat >> 3);
  int bx = swz % 6, by = swz / 6;        // bx fastest -> A-panel L2 reuse per XCD

  const float*    pAf = xf + (size_t)(by*256 + 32*w + l15)*512 + g*8;
  const ushort_t* pB  = wh + ((size_t)bx*256 + (size_t)(32*w) + l15)*512 + g*8;

  f32x4 acc[8][4];
  #pragma unroll
  for (int r = 0; r < 8; r++)
    #pragma unroll
    for (int c = 0; c < 4; c++) acc[r][c] = (f32x4){0.f, 0.f, 0.f, 0.f};

  f32x4 a0[4], a1[4];   // in-flight A fragments: [q*2+kh]

  // prologue: tile 0. A: f32 loads -> cvt -> ds_write; B: gl_lds16.
  #pragma unroll
  for (int q = 0; q < 2; q++)
    #pragma unroll
    for (int kh2 = 0; kh2 < 2; kh2++) {
      const float* p = pAf + q*8192 + kh2*32;
      a0[q*2 + kh2] = *(const f32x4*)p;
      a1[q*2 + kh2] = *(const f32x4*)(p + 4);
    }
  gl_lds16(pB +        0, lds + 16384 + ((2*w + 0)*2 + 0)*512);
  gl_lds16(pB +       32, lds + 16384 + ((2*w + 0)*2 + 1)*512);
  gl_lds16(pB + 8192 + 0, lds + 16384 + ((2*w + 1)*2 + 0)*512);
  gl_lds16(pB + 8192 +32, lds + 16384 + ((2*w + 1)*2 + 1)*512);
  #pragma unroll
  for (int q = 0; q < 2; q++)
    #pragma unroll
    for (int kh2 = 0; kh2 < 2; kh2++) {
      int i = q*2 + kh2;
      s16x8 pk;
      #pragma unroll
      for (int j = 0; j < 4; j++) {
        pk[j]     = (short)f2bf(a0[i][j]);
        pk[4 + j] = (short)f2bf(a1[i][j]);
      }
      *(s16x8*)&lds[((2*w + q)*2 + kh2)*512 + lane*8] = pk;
    }
  asm volatile("s_waitcnt vmcnt(0) lgkmcnt(0)" ::: "memory");
  __builtin_amdgcn_s_barrier();

  for (int tau = 0; tau < 8; ++tau) {
    ushort_t* bufR = lds + (tau & 1)*32768;
    ushort_t* bufW = lds + ((tau & 1) ^ 1)*32768;
    if (tau < 7) {                       // issue-early: A f32 loads + B gl_lds16
      int ko = (tau + 1)*64;
      #pragma unroll
      for (int q = 0; q < 2; q++)
        #pragma unroll
        for (int kh2 = 0; kh2 < 2; kh2++) {
          const float* p = pAf + q*8192 + ko + kh2*32;
          a0[q*2 + kh2] = *(const f32x4*)p;
          a1[q*2 + kh2] = *(const f32x4*)(p + 4);
        }
      gl_lds16(pB + ko,            bufW + 16384 + ((2*w + 0)*2 + 0)*512);
      gl_lds16(pB + ko + 32,       bufW + 16384 + ((2*w + 0)*2 + 1)*512);
      gl_lds16(pB + 8192 + ko,     bufW + 16384 + ((2*w + 1)*2 + 0)*512);
      gl_lds16(pB + 8192 + ko +32, bufW + 16384 + ((2*w + 1)*2 + 1)*512);
    }
    s16x8 af[4][2], bf[4][2];
    #pragma unroll
    for (int t = 0; t < 4; t++)
      #pragma unroll
      for (int kh2 = 0; kh2 < 2; kh2++) {
        af[t][kh2] = *(const s16x8*)&bufR[((wm*8 + t)*2 + kh2)*512 + lane*8];
        bf[t][kh2] = *(const s16x8*)&bufR[16384 + ((wn*4 + t)*2 + kh2)*512 + lane*8];
      }
    __builtin_amdgcn_s_barrier();
    asm volatile("s_waitcnt lgkmcnt(0)" ::: "memory");
    __builtin_amdgcn_sched_barrier(0);
    __builtin_amdgcn_s_setprio(1);
    #pragma unroll
    for (int t = 0; t < 4; t++)
      #pragma unroll
      for (int tb = 0; tb < 4; tb++) {
        acc[t][tb] = __builtin_amdgcn_mfma_f32_16x16x32_bf16(af[t][0], bf[tb][0], acc[t][tb], 0, 0, 0);
        acc[t][tb] = __builtin_amdgcn_mfma_f32_16x16x32_bf16(af[t][1], bf[tb][1], acc[t][tb], 0, 0, 0);
      }
    __builtin_amdgcn_s_setprio(0);
    s16x8 ag[4][2];
    #pragma unroll
    for (int t = 0; t < 4; t++)
      #pragma unroll
      for (int kh2 = 0; kh2 < 2; kh2++)
        ag[t][kh2] = *(const s16x8*)&bufR[((wm*8 + 4 + t)*2 + kh2)*512 + lane*8];
    asm volatile("s_waitcnt lgkmcnt(0)" ::: "memory");
    __builtin_amdgcn_sched_barrier(0);
    __builtin_amdgcn_s_setprio(1);
    #pragma unroll
    for (int t = 0; t < 4; t++)
      #pragma unroll
      for (int tb = 0; tb < 4; tb++) {
        acc[4 + t][tb] = __builtin_amdgcn_mfma_f32_16x16x32_bf16(ag[t][0], bf[tb][0], acc[4 + t][tb], 0, 0, 0);
        acc[4 + t][tb] = __builtin_amdgcn_mfma_f32_16x16x32_bf16(ag[t][1], bf[tb][1], acc[4 + t][tb], 0, 0, 0);
      }
    __builtin_amdgcn_s_setprio(0);
    if (tau < 7) {                       // write-late: cvt + ds_write A(tau+1)
      #pragma unroll
      for (int q = 0; q < 2; q++)
        #pragma unroll
        for (int kh2 = 0; kh2 < 2; kh2++) {
          int i = q*2 + kh2;
          s16x8 pk;
          #pragma unroll
          for (int j = 0; j < 4; j++) {
            pk[j]     = (short)f2bf(a0[i][j]);
            pk[4 + j] = (short)f2bf(a1[i][j]);
          }
          *(s16x8*)&bufW[((2*w + q)*2 + kh2)*512 + lane*8] = pk;
        }
    }
    asm volatile("s_waitcnt vmcnt(0) lgkmcnt(0)" ::: "memory");
    __builtin_amdgcn_s_barrier();
  }

  // ---- epilogue: acc -> LDS (swizzled, conflict-free), then coalesced stores.
  asm volatile("" ::: "memory");
  const int sel = bx >> 1;
  if (sel < 2) {
    #pragma unroll
    for (int ra = 0; ra < 8; ra++)
      #pragma unroll
      for (int tb = 0; tb < 4; tb++)
        #pragma unroll
        for (int j = 0; j < 4; j++) {
          int row = wm*128 + ra*16 + g*4 + j;
          int col = wn*64 + tb*16 + l15;
          int r = (row >> 6)*8 + (col >> 5);
          int n = row & 63, d = col & 31;
          int byte = r*4096 + ((n*64 + d*2) ^ ((n & 12) << 3));
          *(ushort_t*)((char*)lds + byte) = f2bf(acc[ra][tb][j]);
        }
  } else {
    #pragma unroll
    for (int ra = 0; ra < 8; ra++)
      #pragma unroll
      for (int tb = 0; tb < 4; tb++) {
        int row0 = wm*128 + ra*16 + g*4;
        int col = wn*64 + tb*16 + l15;
        int r = (row0 >> 6)*8 + (col >> 5);
        int n0 = row0 & 63, d = col & 31;
        u64_t pk = (u64_t)f2bf(acc[ra][tb][0])
                 | ((u64_t)f2bf(acc[ra][tb][1]) << 16)
                 | ((u64_t)f2bf(acc[ra][tb][2]) << 32)
                 | ((u64_t)f2bf(acc[ra][tb][3]) << 48);
        int byte = r*4096 + ((d*128 + n0*2) ^ ((d & 7) << 4) ^ (((((d >> 3) ^ (n0 >> 3))) & 1) << 6));
        *(u64_t*)((char*)lds + byte) = pk;
      }
  }
  asm volatile("s_waitcnt lgkmcnt(0)" ::: "memory");
  __builtin_amdgcn_s_barrier();
  ushort_t* dst = (sel == 0) ? qh : (sel == 1) ? kh : vt;
  const int hbase = (bx & 1) * 8;
  #pragma unroll
  for (int it = 0; it < 16; it++) {
    int cg = it*512 + tid;
    int r = cg >> 8, inner = cg & 255;
    int byte;
    if (sel < 2) byte = r*4096 + ((inner*16) ^ (((inner >> 2) & 12) << 3));
    else         byte = r*4096 + ((inner*16) ^ (((inner >> 3) & 7) << 4) ^ ((((inner >> 6) ^ inner) & 1) << 6));
    s16x8 v = *(const s16x8*)((const char*)lds + byte);
    int b = by*4 + (r >> 3), h = hbase + (r & 7);
    *(s16x8*)&dst[(size_t)(b*16 + h)*2048 + inner*8] = v;
  }
}

// ================= proj GEMM: same 256x256 loop, f32 epilogue in 2 passes (swizzled).
__global__ __launch_bounds__(512, 2) void k_gemm_proj(
    const ushort_t* __restrict__ ah, const ushort_t* __restrict__ wh,
    const float* __restrict__ pb, float* __restrict__ out) {
  extern __shared__ __align__(16) ushort_t lds[];
  const int tid = threadIdx.x, w = tid >> 6, lane = tid & 63;
  const int g = lane >> 4, l15 = lane & 15;
  const int wm = w >> 2, wn = w & 3;
  int flat = blockIdx.x;                 // 784 = 8*98, bijective XCD swizzle
  int swz = (flat & 7) * 98 + (flat >> 3);
  int bx = swz & 1, by = swz >> 1;

  const ushort_t* pA = ah + ((size_t)by*256 + (size_t)(2*w)*16 + l15)*512 + g*8;
  const ushort_t* pB = wh + ((size_t)bx*256 + (size_t)(2*w)*16 + l15)*512 + g*8;

  f32x4 acc[8][4];
  #pragma unroll
  for (int r = 0; r < 8; r++)
    #pragma unroll
    for (int c = 0; c < 4; c++) acc[r][c] = (f32x4){0.f, 0.f, 0.f, 0.f};

  gemm256_loop(lds, pA, pB, w, lane, wm, wn, acc);

  asm volatile("" ::: "memory");
  #pragma unroll
  for (int p = 0; p < 2; p++) {
    if (p) { asm volatile("" ::: "memory"); __builtin_amdgcn_s_barrier(); }
    if (wm == p) {
      #pragma unroll
      for (int ra = 0; ra < 8; ra++)
        #pragma unroll
        for (int tb = 0; tb < 4; tb++)
          #pragma unroll
          for (int j = 0; j < 4; j++) {
            int row = ra*16 + g*4 + j;          // local 0-127
            int col = wn*64 + tb*16 + l15;
            int byte = (row*1024 + col*4) ^ ((row & 12) << 2) ^ ((row & 8) << 3);
            *(float*)((char*)lds + byte) = acc[ra][tb][j];
          }
    }
    asm volatile("s_waitcnt lgkmcnt(0)" ::: "memory");
    __builtin_amdgcn_s_barrier();
    #pragma unroll
    for (int it = 0; it < 16; it++) {
      int cg = it*512 + tid;
      int row = cg >> 6, c16 = cg & 63;
      int byte = row*1024 + ((c16*16) ^ ((row & 12) << 2) ^ ((row & 8) << 3));
      f32x4 v = *(const f32x4*)((const char*)lds + byte);
      int ncol = bx*256 + c16*4;
      f32x4 pbv = *(const f32x4*)&pb[ncol];
      v = v + pbv;
      *(f32x4*)&out[(size_t)(by*256 + p*128 + row)*512 + ncol] = v;
    }
  }
}

// ---------- kernel 3: per-(b,h) attention, plain bf16, one wave per head-window.
__global__ __launch_bounds__(256) void k_attn(
    const ushort_t* __restrict__ qh, const ushort_t* __restrict__ kh,
    const ushort_t* __restrict__ vt, const float* __restrict__ bias,
    ushort_t* __restrict__ aoh) {
  __shared__ ushort_t plds[4][64*72];
  const int tid = threadIdx.x, w = tid >> 6, lane = tid & 63;
  const int g = lane >> 4, l15 = lane & 15;
  const int gw = blockIdx.x * 4 + w;      // 0 .. 25087
  const int b = gw >> 4, h = gw & 15;
  const size_t base = (size_t)(b*16 + h) * 2048;

  s16x8 qf[4], kf[4];
  #pragma unroll
  for (int t = 0; t < 4; t++) {
    size_t o = base + (size_t)(t*16 + l15)*32 + g*8;
    qf[t] = *(const s16x8*)&qh[o];
    kf[t] = *(const s16x8*)&kh[o];
  }
  s16x8 vf[2][2];
  #pragma unroll
  for (int kt = 0; kt < 2; kt++)
    #pragma unroll
    for (int nt = 0; nt < 2; nt++)
      vf[kt][nt] = *(const s16x8*)&vt[base + (size_t)(nt*16 + l15)*64 + kt*32 + g*8];

  f32x4 s[4][4];
  #pragma unroll
  for (int r = 0; r < 4; r++)
    #pragma unroll
    for (int c = 0; c < 4; c++) s[r][c] = (f32x4){0.f,0.f,0.f,0.f};
  #pragma unroll
  for (int r = 0; r < 4; r++)
    #pragma unroll
    for (int c = 0; c < 4; c++)
      s[r][c] = __builtin_amdgcn_mfma_f32_16x16x32_bf16(qf[r], kf[c], s[r][c], 0, 0, 0);

  const float invs = 0.17677669529663687f;  // 1/sqrt(32)
  const float* bh_ = bias + ((size_t)h << 12);
  #pragma unroll
  for (int r = 0; r < 4; r++)
    #pragma unroll
    for (int c = 0; c < 4; c++)
      #pragma unroll
      for (int j = 0; j < 4; j++) {
        int rr = r*16 + g*4 + j, cc = c*16 + l15;
        s[r][c][j] = s[r][c][j]*invs + bh_[rr*64 + cc];
      }

  #pragma unroll
  for (int r = 0; r < 4; r++)
    #pragma unroll
    for (int j = 0; j < 4; j++) {
      float mx = fmaxf(fmaxf(s[r][0][j], s[r][1][j]), fmaxf(s[r][2][j], s[r][3][j]));
      mx = fmaxf(mx, __shfl_xor(mx, 1));
      mx = fmaxf(mx, __shfl_xor(mx, 2));
      mx = fmaxf(mx, __shfl_xor(mx, 4));
      mx = fmaxf(mx, __shfl_xor(mx, 8));
      float p0 = __expf(s[r][0][j]-mx), p1 = __expf(s[r][1][j]-mx);
      float p2 = __expf(s[r][2][j]-mx), p3 = __expf(s[r][3][j]-mx);
      float sum = p0 + p1 + p2 + p3;
      sum += __shfl_xor(sum, 1);
      sum += __shfl_xor(sum, 2);
      sum += __shfl_xor(sum, 4);
      sum += __shfl_xor(sum, 8);
      float rv = 1.0f / sum;
      s[r][0][j] = p0*rv; s[r][1][j] = p1*rv; s[r][2][j] = p2*rv; s[r][3][j] = p3*rv;
    }

  ushort_t* Pm = plds[w];
  #pragma unroll
  for (int r = 0; r < 4; r++)
    #pragma unroll
    for (int c = 0; c < 4; c++)
      #pragma unroll
      for (int j = 0; j < 4; j++) {
        int rr = r*16 + g*4 + j, cc = c*16 + l15;
        Pm[rr*72 + cc] = f2bf(s[r][c][j]);
      }
  s16x8 pf[4][2];
  #pragma unroll
  for (int ta = 0; ta < 4; ta++)
    #pragma unroll
    for (int kt = 0; kt < 2; kt++)
      pf[ta][kt] = *(const s16x8*)&Pm[(ta*16 + l15)*72 + kt*32 + g*8];

  f32x4 o[4][2];
  #pragma unroll
  for (int ta = 0; ta < 4; ta++)
    #pragma unroll
    for (int nt = 0; nt < 2; nt++) o[ta][nt] = (f32x4){0.f,0.f,0.f,0.f};
  #pragma unroll
  for (int ta = 0; ta < 4; ta++)
    #pragma unroll
    for (int nt = 0; nt < 2; nt++)
      #pragma unroll
      for (int kt = 0; kt < 2; kt++)
        o[ta][nt] = __builtin_amdgcn_mfma_f32_16x16x32_bf16(pf[ta][kt], vf[kt][nt], o[ta][nt], 0, 0, 0);

  #pragma unroll
  for (int ta = 0; ta < 4; ta++)
    #pragma unroll
    for (int nt = 0; nt < 2; nt++)
      #pragma unroll
      for (int j = 0; j < 4; j++) {
        int rr = ta*16 + g*4 + j, dd = nt*16 + l15;
        aoh[((size_t)b*64 + rr)*512 + h*32 + dd] = f2bf(o[ta][nt][j]);
      }
}

extern "C" void kernel_launch(void* const* d_in, const int* in_sizes, int n_in,
                              void* d_out, int out_size, void* d_ws, size_t ws_size,
                              hipStream_t stream) {
  const float* x      = (const float*)d_in[0];
  const float* qkv_w  = (const float*)d_in[1];
  const float* table  = (const float*)d_in[2];
  const float* proj_w = (const float*)d_in[3];
  const float* proj_b = (const float*)d_in[4];
  const int*   rel_idx = (const int*)d_in[5];

  const size_t S1 = S1_ELEMS;
  const size_t need = (4*S1 + 786432 + 262144)*sizeof(ushort_t) + 65536*sizeof(float);
  if (ws_size < need) return;

  ushort_t* qh  = (ushort_t*)d_ws;
  ushort_t* kh  = qh + S1;
  ushort_t* vt  = kh + S1;
  ushort_t* aoh = vt + S1;
  ushort_t* wqh = aoh + S1;
  ushort_t* wph = wqh + 786432;
  float*    bias = (float*)(wph + 262144);

  hipFuncSetAttribute((const void*)k_gemm_qkv,
                      hipFuncAttributeMaxDynamicSharedMemorySize, 131072);
  hipFuncSetAttribute((const void*)k_gemm_proj,
                      hipFuncAttributeMaxDynamicSharedMemorySize, 131072);

  k_convert_hi<<<768, 256, 0, stream>>>(qkv_w, wqh, 196608);
  k_convert_hi<<<256, 256, 0, stream>>>(proj_w, wph, 65536);
  k_bias<<<256, 256, 0, stream>>>(table, rel_idx, bias);
  k_gemm_qkv<<<2352, 512, 131072, stream>>>(x, wqh, qh, kh, vt);
  k_attn<<<6272, 256, 0, stream>>>(qh, kh, vt, bias, aoh);
  k_gemm_proj<<<784, 512, 131072, stream>>>(aoh, wph, proj_b, (float*)d_out);
}